// Round 1
// baseline (154.059 us; speedup 1.0000x reference)
//
#include <hip/hip_runtime.h>

// Problem: B=256, C=2048, H*W=128, NUM_CLASSES=10000
// Outputs (fp32, concat): logits[256*10000], logits[256*10000],
//                         neck_feat[256*2048], new_weight[256] (== 1.0)
// targets are dead (new_weight is analytically all-ones).

#define OUT1_OFF (256 * 10000)
#define FEAT_OFF (2 * 256 * 10000)
#define NW_OFF   (2 * 256 * 10000 + 256 * 2048)

typedef __attribute__((ext_vector_type(4))) float f32x4;
typedef __attribute__((ext_vector_type(8))) short bf16x8;
typedef __attribute__((ext_vector_type(4))) unsigned int u32x4;

__device__ inline unsigned short f2bf(float x) {
    unsigned u = __float_as_uint(x);
    return (unsigned short)((u + 0x7FFFu + ((u >> 16) & 1u)) >> 16);
}
__device__ inline unsigned pk2bf(float lo, float hi) {
    unsigned a = __float_as_uint(lo), b = __float_as_uint(hi);
    unsigned ra = (a + 0x7FFFu + ((a >> 16) & 1u)) >> 16;
    unsigned rb = (b + 0x7FFFu + ((b >> 16) & 1u)) & 0xFFFF0000u;
    return ra | rb;
}

// ---------------------------------------------------------------------------
// Kernel 1: global average pool over H*W=128 contiguous floats per (b,c) row.
// Writes: out[FEAT..] fp32, ws A in bf16 fragment-major layout
//   elem (m=b, k=c) at ((mt*256 + kc)*16 + r)*8 + ke
//   mt=m>>4, kc=k>>3, r=m&15, ke=k&7   (16B chunk index = (mt*256+kc)*16+r)
// Also writes new_weight = 1.0 (block 0).
// ---------------------------------------------------------------------------
__global__ __launch_bounds__(256) void pool_kernel(
    const float* __restrict__ f, float* __restrict__ out,
    unsigned short* __restrict__ wsA) {
    int tid = threadIdx.x;
    int row = blockIdx.x * 8 + (tid >> 5);  // row = b*2048 + c, 524288 rows
    int l = tid & 31;
    const float4* src = (const float4*)(f + (size_t)row * 128);
    float4 v = src[l];
    float s = v.x + v.y + v.z + v.w;
#pragma unroll
    for (int off = 16; off >= 1; off >>= 1) s += __shfl_xor(s, off);
    float mean = s * (1.0f / 128.0f);
    if (l == 0) {
        out[FEAT_OFF + row] = mean;
        int b = row >> 11;
        int c = row & 2047;
        int idx = (((b >> 4) * 256 + (c >> 3)) * 16 + (b & 15)) * 8 + (c & 7);
        wsA[idx] = f2bf(mean);
    }
    if (blockIdx.x == 0) out[NW_OFF + tid] = 1.0f;
}

// ---------------------------------------------------------------------------
// Kernel 2: logits = A(256x2048, bf16) * W(10000x2048, fp32->bf16)^T
// BM=64, BN=64, BK=64. 256 threads = 4 waves (2x2), wave tile 32x32
// (2x2 fragments of 16x16x32 MFMA). Fragment-major LDS: slot = mf*128+kg*16+r.
// Writes the result to out[0..] and out[OUT1_OFF..].
// ---------------------------------------------------------------------------
__global__ __launch_bounds__(256) void gemm_kernel(
    const unsigned short* __restrict__ wsA, const float* __restrict__ W,
    float* __restrict__ out) {
    __shared__ u32x4 As[512];  // 8 KB
    __shared__ u32x4 Bs[512];  // 8 KB

    int tid = threadIdx.x;
    int mblk = blockIdx.x;       // 0..3   (m0 = mblk*64)
    int n0 = blockIdx.y * 64;    // 0..156 (last tile partially valid)
    int wid = tid >> 6;
    int lane = tid & 63;
    int wm = wid >> 1, wn = wid & 1;
    int r = lane & 15, kqu = lane >> 4;

    const u32x4* A16 = (const u32x4*)wsA;

    f32x4 acc[2][2];
#pragma unroll
    for (int i = 0; i < 2; ++i)
#pragma unroll
        for (int j = 0; j < 2; ++j) acc[i][j] = (f32x4){0.f, 0.f, 0.f, 0.f};

    for (int kt = 0; kt < 32; ++kt) {
        int k0 = kt * 64;
        // ---- stage A (bf16, already fragment-major in global) ----
#pragma unroll
        for (int i = 0; i < 2; ++i) {
            int ci = tid + i * 256;
            int mt = mblk * 4 + (ci >> 7);
            int kc = (k0 >> 3) + ((ci >> 4) & 7);
            As[ci] = A16[(mt * 256 + kc) * 16 + (ci & 15)];
        }
        // ---- stage B (fp32 -> bf16 convert on the fly) ----
#pragma unroll
        for (int i = 0; i < 2; ++i) {
            int ci = tid + i * 256;
            int nr = n0 + (((ci >> 7) << 4) | (ci & 15));
            if (nr > 9999) nr = 9999;  // clamp; stores are predicated
            int kg = (ci >> 4) & 7;
            const float4* wp = (const float4*)(W + (size_t)nr * 2048 + k0 + kg * 8);
            float4 wa = wp[0], wb = wp[1];
            u32x4 p;
            p.x = pk2bf(wa.x, wa.y);
            p.y = pk2bf(wa.z, wa.w);
            p.z = pk2bf(wb.x, wb.y);
            p.w = pk2bf(wb.z, wb.w);
            Bs[ci] = p;
        }
        __syncthreads();
        // ---- MFMA ----
#pragma unroll
        for (int ks = 0; ks < 2; ++ks) {
            bf16x8 a[2], b[2];
#pragma unroll
            for (int i = 0; i < 2; ++i) {
                a[i] = *((const bf16x8*)&As[((wm * 2 + i) * 8 + ks * 4 + kqu) * 16 + r]);
                b[i] = *((const bf16x8*)&Bs[((wn * 2 + i) * 8 + ks * 4 + kqu) * 16 + r]);
            }
#pragma unroll
            for (int i = 0; i < 2; ++i)
#pragma unroll
                for (int j = 0; j < 2; ++j)
                    acc[i][j] = __builtin_amdgcn_mfma_f32_16x16x32_bf16(
                        a[i], b[j], acc[i][j], 0, 0, 0);
        }
        __syncthreads();
    }

    // ---- epilogue: C and C*SCALE (SCALE=1) ----
#pragma unroll
    for (int i = 0; i < 2; ++i) {
#pragma unroll
        for (int j = 0; j < 2; ++j) {
            int n = n0 + (wn * 2 + j) * 16 + r;
            if (n < 10000) {
#pragma unroll
                for (int q = 0; q < 4; ++q) {
                    int m = mblk * 64 + (wm * 2 + i) * 16 + kqu * 4 + q;
                    float v = acc[i][j][q];
                    out[(size_t)m * 10000 + n] = v;
                    out[OUT1_OFF + (size_t)m * 10000 + n] = v;
                }
            }
        }
    }
}

extern "C" void kernel_launch(void* const* d_in, const int* in_sizes, int n_in,
                              void* d_out, int out_size, void* d_ws, size_t ws_size,
                              hipStream_t stream) {
    const float* feats = (const float*)d_in[0];
    // d_in[1] = targets (int32) — provably unused (new_weight == ones)
    const float* weight = (const float*)d_in[2];
    float* out = (float*)d_out;
    unsigned short* wsA = (unsigned short*)d_ws;  // 256*2048 bf16 = 1 MB

    pool_kernel<<<65536, 256, 0, stream>>>(feats, out, wsA);
    gemm_kernel<<<dim3(4, 157), 256, 0, stream>>>(wsA, weight, out);
}

// Round 2
// 104.964 us; speedup vs baseline: 1.4677x; 1.4677x over previous
//
#include <hip/hip_runtime.h>

// B=256, C=2048, H*W=128, NUM_CLASSES=10000
// Outputs (fp32, concat): logits[256*10000], logits[256*10000],
//                         neck_feat[256*2048], new_weight[256] (== 1.0 analytically)
// targets are dead.

#define OUT1_OFF (256 * 10000)
#define FEAT_OFF (2 * 256 * 10000)
#define NW_OFF   (2 * 256 * 10000 + 256 * 2048)

typedef __attribute__((ext_vector_type(4))) float f32x4;
typedef __attribute__((ext_vector_type(8))) short bf16x8;
typedef __attribute__((ext_vector_type(4))) unsigned int u32x4;

__device__ inline unsigned pk2bf(float lo, float hi) {
    unsigned a = __float_as_uint(lo), b = __float_as_uint(hi);
    unsigned ra = (a + 0x7FFFu + ((a >> 16) & 1u)) >> 16;
    unsigned rb = (b + 0x7FFFu + ((b >> 16) & 1u)) & 0xFFFF0000u;
    return ra | rb;
}

__device__ inline void gload_lds16(const void* g, void* l) {
    __builtin_amdgcn_global_load_lds(
        (const __attribute__((address_space(1))) void*)g,
        (__attribute__((address_space(3))) void*)l, 16, 0, 0);
}

// ---------------------------------------------------------------------------
// Kernel 1: mean over H*W=128 floats per (b,c) row. 32-lane group handles 2
// consecutive rows (ILP). Writes feat (fp32) + wsA bf16 in MFMA fragment-major
// layout: elem (m=b,k=c) at chunk ((b>>4)*256 + (c>>3))*16 + (b&15), byte 2*(c&7).
// ---------------------------------------------------------------------------
__global__ __launch_bounds__(256) void pool_kernel(
    const float* __restrict__ f, float* __restrict__ out,
    unsigned int* __restrict__ wsA32) {
    int tid = threadIdx.x;
    int g = tid >> 5;
    int l = tid & 31;
    int r0 = blockIdx.x * 16 + g * 2;  // rows r0, r0+1 (r0 even)
    const f32x4* s0 = (const f32x4*)(f + (size_t)r0 * 128);
    f32x4 v0 = s0[l];
    f32x4 v1 = s0[l + 32];
    float a = v0[0] + v0[1] + v0[2] + v0[3];
    float b = v1[0] + v1[1] + v1[2] + v1[3];
#pragma unroll
    for (int off = 16; off >= 1; off >>= 1) {
        a += __shfl_xor(a, off);
        b += __shfl_xor(b, off);
    }
    if (l == 0) {
        float m0 = a * (1.0f / 128.0f), m1 = b * (1.0f / 128.0f);
        float2 fv; fv.x = m0; fv.y = m1;
        *(float2*)&out[FEAT_OFF + r0] = fv;
        int bb = r0 >> 11, c = r0 & 2047;
        int chunk = ((bb >> 4) * 256 + (c >> 3)) * 16 + (bb & 15);
        wsA32[chunk * 4 + ((c & 7) >> 1)] = pk2bf(m0, m1);
    }
    if (blockIdx.x == 0) out[NW_OFF + tid] = 1.0f;
}

// ---------------------------------------------------------------------------
// Kernel 2: logits = A(256x2048 bf16) * W(10000x2048 fp32->bf16)^T
// BM=256 (all M), BN=64, BK=64. 512 threads = 8 waves (4m x 2n), wave tile
// 64x32 = 4x2 frags of 16x16x32. Triple-buffered LDS, depth-2 in flight,
// counted vmcnt(6), one raw s_barrier per K-step.
// A staged via global_load_lds (fragment-major in ws -> linear LDS).
// B reg-staged: fp32 load 2 tiles early, convert+ds_write 1 tile early.
// ---------------------------------------------------------------------------
__global__ __launch_bounds__(512) void gemm_kernel(
    const u32x4* __restrict__ A16, const float* __restrict__ W,
    float* __restrict__ out) {
    __shared__ u32x4 As[3][2048];  // 32 KB per buf
    __shared__ u32x4 Bs[3][512];   // 8 KB per buf  -> 120 KB total

    int tid = threadIdx.x;
    int n0 = blockIdx.x * 64;
    int wid = tid >> 6, lane = tid & 63;
    int wm = wid >> 1, wn = wid & 1;
    int r = lane & 15, kqu = lane >> 4;

    // A staging: 4 chunks/thread, LDS ci = tid + i*512 (wave-linear), global
    // chunk = ((ci>>7)*256 + kt*8 + ((ci>>4)&7))*16 + (ci&15)
    const u32x4* ga[4];
#pragma unroll
    for (int i = 0; i < 4; ++i) {
        int ci = tid + i * 512;
        ga[i] = A16 + (((ci >> 7) * 256 + ((ci >> 4) & 7)) * 16 + (ci & 15));
    }
    // B staging: thread tid -> chunk ci=tid: row nr, 8 k-elems at kg*8
    int nr = n0 + (((tid >> 7) << 4) | (tid & 15));
    if (nr > 9999) nr = 9999;  // clamp (stores predicated)
    int kg = (tid >> 4) & 7;
    const f32x4* gb = (const f32x4*)(W + (size_t)nr * 2048 + kg * 8);

    f32x4 acc[4][2];
#pragma unroll
    for (int i = 0; i < 4; ++i)
#pragma unroll
        for (int j = 0; j < 2; ++j) acc[i][j] = (f32x4){0.f, 0.f, 0.f, 0.f};

    f32x4 rbA0, rbA1, rbB0, rbB1;

#define STAGE_A(kt, buf)                                           \
    {                                                              \
        _Pragma("unroll") for (int i = 0; i < 4; ++i)              \
            gload_lds16(ga[i] + (kt) * 128, &As[buf][tid + i * 512]); \
    }
#define LOAD_B(kt, r0_, r1_)                \
    {                                       \
        r0_ = gb[(kt) * 16];                \
        r1_ = gb[(kt) * 16 + 1];            \
    }
#define PACK_B(buf, r0_, r1_)                              \
    {                                                      \
        u32x4 p;                                           \
        p.x = pk2bf(r0_[0], r0_[1]);                       \
        p.y = pk2bf(r0_[2], r0_[3]);                       \
        p.z = pk2bf(r1_[0], r1_[1]);                       \
        p.w = pk2bf(r1_[2], r1_[3]);                       \
        Bs[buf][tid] = p;                                  \
    }

    // ---- prologue: tiles 0 and 1 in flight ----
    STAGE_A(0, 0); LOAD_B(0, rbA0, rbA1);
    STAGE_A(1, 1); LOAD_B(1, rbB0, rbB1);
    asm volatile("s_waitcnt vmcnt(6)" ::: "memory");  // tile 0 landed
    __builtin_amdgcn_sched_barrier(0);
    PACK_B(0, rbA0, rbA1);
    asm volatile("s_waitcnt lgkmcnt(0)" ::: "memory");
    __builtin_amdgcn_sched_barrier(0);
    __builtin_amdgcn_s_barrier();
    __builtin_amdgcn_sched_barrier(0);

    for (int kt = 0; kt < 32; ++kt) {
        int cur = kt % 3;
        // issue tile kt+2 (A -> LDS DMA, B -> regs)
        if (kt <= 29) {
            int nx2 = (kt + 2) % 3;
            STAGE_A(kt + 2, nx2);
            if (kt & 1) { LOAD_B(kt + 2, rbB0, rbB1); }
            else        { LOAD_B(kt + 2, rbA0, rbA1); }
        }
        // compute tile kt
#pragma unroll
        for (int ks = 0; ks < 2; ++ks) {
            int kcl = ks * 4 + kqu;
            bf16x8 av[4], bv[2];
#pragma unroll
            for (int i = 0; i < 4; ++i)
                av[i] = *(const bf16x8*)&As[cur][(wm * 4 + i) * 128 + kcl * 16 + r];
#pragma unroll
            for (int j = 0; j < 2; ++j)
                bv[j] = *(const bf16x8*)&Bs[cur][(wn * 2 + j) * 128 + kcl * 16 + r];
#pragma unroll
            for (int i = 0; i < 4; ++i)
#pragma unroll
                for (int j = 0; j < 2; ++j)
                    acc[i][j] = __builtin_amdgcn_mfma_f32_16x16x32_bf16(
                        av[i], bv[j], acc[i][j], 0, 0, 0);
        }
        // wait tile kt+1 (6 newest ops are tile kt+2's)
        if (kt <= 29) { asm volatile("s_waitcnt vmcnt(6)" ::: "memory"); }
        else          { asm volatile("s_waitcnt vmcnt(0)" ::: "memory"); }
        __builtin_amdgcn_sched_barrier(0);
        if (kt <= 30) {
            int nx1 = (kt + 1) % 3;
            if (kt & 1) { PACK_B(nx1, rbA0, rbA1); }
            else        { PACK_B(nx1, rbB0, rbB1); }
            asm volatile("s_waitcnt lgkmcnt(0)" ::: "memory");
            __builtin_amdgcn_sched_barrier(0);
            __builtin_amdgcn_s_barrier();  // tile kt+1 ready for everyone
        }
        __builtin_amdgcn_sched_barrier(0);
    }

    // ---- epilogue: C and C*SCALE (SCALE=1) ----
#pragma unroll
    for (int i = 0; i < 4; ++i)
#pragma unroll
        for (int j = 0; j < 2; ++j) {
            int n = n0 + (wn * 2 + j) * 16 + r;
            if (n < 10000) {
                int mbase = (wm * 4 + i) * 16 + kqu * 4;
#pragma unroll
                for (int q = 0; q < 4; ++q) {
                    float v = acc[i][j][q];
                    size_t off = (size_t)(mbase + q) * 10000 + n;
                    out[off] = v;
                    out[OUT1_OFF + off] = v;
                }
            }
        }
#undef STAGE_A
#undef LOAD_B
#undef PACK_B
}

extern "C" void kernel_launch(void* const* d_in, const int* in_sizes, int n_in,
                              void* d_out, int out_size, void* d_ws, size_t ws_size,
                              hipStream_t stream) {
    const float* feats = (const float*)d_in[0];
    // d_in[1] = targets (int32) — dead (new_weight == ones analytically)
    const float* weight = (const float*)d_in[2];
    float* out = (float*)d_out;

    pool_kernel<<<32768, 256, 0, stream>>>(feats, out, (unsigned int*)d_ws);
    gemm_kernel<<<157, 512, 0, stream>>>((const u32x4*)d_ws, weight, out);
}